// Round 15
// baseline (289.317 us; speedup 1.0000x reference)
//
#include <hip/hip_runtime.h>
#include <hip/hip_bf16.h>
#include <math.h>

#define BB 8
#define PP 768
#define NPRI 76
#define SS 36
#define CIN 64
#define CADJ 72
#define DD 512

#define H0 40
#define W0 100
#define H1 20
#define W1 50
#define H2 10
#define W2 25

typedef __attribute__((ext_vector_type(8))) short bf16x8;
typedef __attribute__((ext_vector_type(4))) short bf16x4;
typedef __attribute__((ext_vector_type(4))) float f32x4;
#define MFMA_BF16 __builtin_amdgcn_mfma_f32_16x16x32_bf16

typedef const __attribute__((address_space(1))) unsigned int* gas_t;
typedef __attribute__((address_space(3))) unsigned int* las_t;

__device__ __forceinline__ __hip_bfloat16 to_bf16(float v) { return __float2bfloat16(v); }
__device__ __forceinline__ float bf2f(__hip_bfloat16 v) { return __bfloat162float(v); }
__device__ __forceinline__ short to_bf16s(float v) {
    __hip_bfloat16 h = __float2bfloat16(v);
    return *reinterpret_cast<short*>(&h);
}
__device__ __forceinline__ float bfs2f(short s) {
    union { unsigned u; float f; } cv;
    cv.u = ((unsigned)(unsigned short)s) << 16;
    return cv.f;
}

// ---- bilinear sample, zeros outside (f32 source) ----
__device__ __forceinline__ float bsample(const float* __restrict__ img, int H, int W,
                                         int C, int c, float x, float y)
{
    float x0f = floorf(x), y0f = floorf(y);
    int x0 = (int)x0f, y0 = (int)y0f;
    float wx1 = x - x0f, wy1 = y - y0f;
    float wx0 = 1.0f - wx1, wy0 = 1.0f - wy1;
    int xc0 = min(max(x0, 0), W - 1);
    int xc1 = min(max(x0 + 1, 0), W - 1);
    int yc0 = min(max(y0, 0), H - 1);
    int yc1 = min(max(y0 + 1, 0), H - 1);
    bool vx0 = (x0 >= 0) && (x0 < W);
    bool vx1 = (x0 + 1 >= 0) && (x0 + 1 < W);
    bool vy0 = (y0 >= 0) && (y0 < H);
    bool vy1 = (y0 + 1 >= 0) && (y0 + 1 < H);
    float w00 = (vx0 && vy0) ? wx0 * wy0 : 0.0f;
    float w01 = (vx1 && vy0) ? wx1 * wy0 : 0.0f;
    float w10 = (vx0 && vy1) ? wx0 * wy1 : 0.0f;
    float w11 = (vx1 && vy1) ? wx1 * wy1 : 0.0f;
    return w00 * img[((size_t)yc0 * W + xc0) * C + c]
         + w01 * img[((size_t)yc0 * W + xc1) * C + c]
         + w10 * img[((size_t)yc1 * W + xc0) * C + c]
         + w11 * img[((size_t)yc1 * W + xc1) * C + c];
}

__device__ __forceinline__ void cast4(__hip_bfloat16* dst, const float* src, long i)
{
    const float4 v = *(const float4*)(src + i * 4);
    bf16x4 pk;
    pk[0] = to_bf16s(v.x); pk[1] = to_bf16s(v.y);
    pk[2] = to_bf16s(v.z); pk[3] = to_bf16s(v.w);
    *(bf16x4*)(dst + i * 4) = pk;
}

// ---- merged weight prep: wfuse | wfuseb | vec4 wcast | bias copy ----
__global__ __launch_bounds__(256) void k_wprep(
    const float* __restrict__ wq, const float* __restrict__ wk, const float* __restrict__ wv,
    const float* __restrict__ wo, const float* __restrict__ cf_w1, const float* __restrict__ cf_w2,
    const float* __restrict__ cls_w1, const float* __restrict__ reg_w1, const float* __restrict__ p_w1,
    const float* __restrict__ bq, const float* __restrict__ bk, const float* __restrict__ bv,
    const float* __restrict__ cls_b1, const float* __restrict__ reg_b1,
    const float* __restrict__ gf_w, const float* __restrict__ dp_w,
    const float* __restrict__ dp_b, const float* __restrict__ gf_b,
    __hip_bfloat16* __restrict__ wqkv, __hip_bfloat16* __restrict__ wo_bf,
    __hip_bfloat16* __restrict__ cf1_bf, __hip_bfloat16* __restrict__ cf2_bf,
    __hip_bfloat16* __restrict__ clsreg_bf, __hip_bfloat16* __restrict__ p1_bf,
    __hip_bfloat16* __restrict__ gfw2, float* __restrict__ b2,
    float* __restrict__ bqkv, float* __restrict__ bclsreg)
{
    __shared__ float dpS[CADJ][CADJ + 1];
    __shared__ float gfr[648];
    const int bid = blockIdx.x;
    const int tid = threadIdx.x;

    if (bid < 512) {
        const int o = bid;
        for (int i = tid; i < CADJ * CADJ; i += 256) dpS[i / CADJ][i % CADJ] = dp_w[i];
        for (int i = tid; i < 648; i += 256) gfr[i] = gf_w[(size_t)o * 648 + i];
        __syncthreads();
        for (int t = tid; t < 672; t += 256) {
            float acc = 0.0f;
            if (t < 648) {
                const int i = t / 72, m = t % 72;
                const float* gr = gfr + i * 72;
#pragma unroll 8
                for (int k = 0; k < 72; ++k) acc = fmaf(gr[k], dpS[k][m], acc);
            }
            gfw2[(size_t)o * 672 + t] = to_bf16(acc);
        }
        return;
    }
    if (bid < 514) {
        const int o = (bid - 512) * 256 + tid;
        if (o < DD) {
            const float* gr = gf_w + (size_t)o * 648;
            float acc = gf_b[o];
            for (int j = 0; j < 648; ++j) acc = fmaf(gr[j], dp_b[j % 72], acc);
            b2[o] = acc;
        }
        return;
    }
    if (bid < 3586) {
        long i = (long)(bid - 514) * 256 + tid;
        if (i < 65536) { cast4(wqkv, wq, i); return; }
        i -= 65536;
        if (i < 65536) { cast4(wqkv + 262144, wk, i); return; }
        i -= 65536;
        if (i < 65536) { cast4(wqkv + 524288, wv, i); return; }
        i -= 65536;
        if (i < 65536) { cast4(wo_bf, wo, i); return; }
        i -= 65536;
        if (i < 131072) { cast4(cf1_bf, cf_w1, i); return; }
        i -= 131072;
        if (i < 131072) { cast4(cf2_bf, cf_w2, i); return; }
        i -= 131072;
        if (i < 65536) { cast4(clsreg_bf, cls_w1, i); return; }
        i -= 65536;
        if (i < 65536) { cast4(clsreg_bf + 262144, reg_w1, i); return; }
        i -= 65536;
        if (i < 131072) { cast4(p1_bf, p_w1, i); return; }
        return;
    }
    for (int i = tid; i < 2560; i += 256) {
        if (i < 512) bqkv[i] = bq[i];
        else if (i < 1024) bqkv[i] = bk[i - 512];
        else if (i < 1536) bqkv[i] = bv[i - 1024];
        else if (i < 2048) bclsreg[i - 1536] = cls_b1[i - 1536];
        else bclsreg[i - 1536] = reg_b1[i - 2048];
    }
}

// ---- fused tiled channel-adjust (+ offset head), level 0, 64 pixels/block ----
__global__ __launch_bounds__(256) void k_adjoff(
    const float* __restrict__ f, const float* __restrict__ caw, const float* __restrict__ cab,
    const float* __restrict__ offw, const float* __restrict__ offb,
    __hip_bfloat16* __restrict__ feout, float* __restrict__ offout, int HW, int do_off)
{
    __shared__ float inS[64][65];
    __shared__ float wS[72][64];
    __shared__ float owS[72][73];
    __shared__ float feS[64][73];
    __shared__ float cabS[72], obS[72];

    const int tid = threadIdx.x;
    const int b = blockIdx.y;
    const int pix0 = blockIdx.x * 64;
    const int cnt = min(64, HW - pix0);
    const int px = tid & 63, og = tid >> 6, o0 = og * 18;

    const float* fb = f + (size_t)b * CIN * HW + pix0;
    for (int i = tid; i < 72 * 64; i += 256) wS[i >> 6][i & 63] = caw[i];
    if (do_off)
        for (int i = tid; i < 72 * 72; i += 256) owS[i / 72][i % 72] = offw[i];
    if (tid < 72) { cabS[tid] = cab[tid]; obS[tid] = do_off ? offb[tid] : 0.f; }
    for (int i = tid; i < 64 * 64; i += 256) {
        const int c = i >> 6, p = i & 63;
        inS[c][p] = (p < cnt) ? fb[(size_t)c * HW + p] : 0.f;
    }
    __syncthreads();

    float acc[18];
#pragma unroll
    for (int j = 0; j < 18; ++j) acc[j] = cabS[o0 + j];
#pragma unroll 4
    for (int c = 0; c < 64; ++c) {
        const float v = inS[c][px];
#pragma unroll
        for (int j = 0; j < 18; ++j) acc[j] = fmaf(v, wS[o0 + j][c], acc[j]);
    }
#pragma unroll
    for (int j = 0; j < 18; ++j) feS[px][o0 + j] = acc[j];
    __syncthreads();

    __hip_bfloat16* feg = feout + ((size_t)b * HW + pix0) * CADJ;
    for (int i = tid; i < cnt * CADJ; i += 256) feg[i] = to_bf16(feS[i / CADJ][i % CADJ]);

    if (!do_off) return;

    float acc2[18];
#pragma unroll
    for (int j = 0; j < 18; ++j) acc2[j] = obS[o0 + j];
#pragma unroll 4
    for (int c = 0; c < 72; ++c) {
        const float v = feS[px][c];
#pragma unroll
        for (int j = 0; j < 18; ++j) acc2[j] = fmaf(v, owS[o0 + j][c], acc2[j]);
    }
    __syncthreads();
#pragma unroll
    for (int j = 0; j < 18; ++j) feS[px][o0 + j] = acc2[j];
    __syncthreads();
    float* ofg = offout + ((size_t)b * HW + pix0) * CADJ;
    for (int i = tid; i < cnt * CADJ; i += 256) ofg[i] = feS[i / CADJ][i % CADJ];
}

// ---- merged: channel-adjust L1+L2 (blocks 0..159) | resize L1+L2 (rest) ----
__global__ __launch_bounds__(256) void k_adjr12(
    const float* __restrict__ f1, const float* __restrict__ f2,
    const float* __restrict__ caw, const float* __restrict__ cab,
    __hip_bfloat16* __restrict__ fe1, __hip_bfloat16* __restrict__ fe2,
    const float* __restrict__ of0, float* __restrict__ of1, float* __restrict__ of2)
{
    const int blk = blockIdx.x;
    const int tid = threadIdx.x;

    if (blk < 160) {
        __shared__ float inS[64][65];
        __shared__ float wS[72][64];
        __shared__ float feS[64][73];
        __shared__ float cabS[72];

        const int bx = blk % 20;
        const int b = blk / 20;
        const float* f;
        __hip_bfloat16* fe;
        int HW, pix0;
        if (bx < 16) { f = f1; fe = fe1; HW = H1 * W1; pix0 = bx * 64; }
        else         { f = f2; fe = fe2; HW = H2 * W2; pix0 = (bx - 16) * 64; }
        const int cnt = min(64, HW - pix0);
        const int px = tid & 63, og = tid >> 6, o0 = og * 18;

        const float* fb = f + (size_t)b * CIN * HW + pix0;
        for (int i = tid; i < 72 * 64; i += 256) wS[i >> 6][i & 63] = caw[i];
        if (tid < 72) cabS[tid] = cab[tid];
        for (int i = tid; i < 64 * 64; i += 256) {
            const int c = i >> 6, p = i & 63;
            inS[c][p] = (p < cnt) ? fb[(size_t)c * HW + p] : 0.f;
        }
        __syncthreads();

        float acc[18];
#pragma unroll
        for (int j = 0; j < 18; ++j) acc[j] = cabS[o0 + j];
#pragma unroll 4
        for (int c = 0; c < 64; ++c) {
            const float v = inS[c][px];
#pragma unroll
            for (int j = 0; j < 18; ++j) acc[j] = fmaf(v, wS[o0 + j][c], acc[j]);
        }
#pragma unroll
        for (int j = 0; j < 18; ++j) feS[px][o0 + j] = acc[j];
        __syncthreads();

        __hip_bfloat16* feg = fe + ((size_t)b * HW + pix0) * CADJ;
        for (int i = tid; i < cnt * CADJ; i += 256) feg[i] = to_bf16(feS[i / CADJ][i % CADJ]);
        return;
    }

    const int T1 = BB * H1 * W1 * CADJ;
    const int T2 = BB * H2 * W2 * CADJ;
    int idx = (blk - 160) * 256 + tid;
    if (idx < T1) {
        const int c = idx % CADJ;
        const int j = (idx / CADJ) % W1;
        const int i = (idx / (CADJ * W1)) % H1;
        const int b = idx / (CADJ * W1 * H1);
        float sy = fminf((float)i * ((float)(H0 - 1) / (float)(H1 - 1)), (float)(H0 - 1));
        float sx = fminf((float)j * ((float)(W0 - 1) / (float)(W1 - 1)), (float)(W0 - 1));
        of1[idx] = bsample(of0 + (size_t)b * H0 * W0 * CADJ, H0, W0, CADJ, c, sx, sy);
        return;
    }
    idx -= T1;
    if (idx >= T2) return;
    const int c = idx % CADJ;
    const int j = (idx / CADJ) % W2;
    const int i = (idx / (CADJ * W2)) % H2;
    const int b = idx / (CADJ * W2 * H2);
    float sy = fminf((float)i * ((float)(H0 - 1) / (float)(H2 - 1)), (float)(H0 - 1));
    float sx = fminf((float)j * ((float)(W0 - 1) / (float)(W2 - 1)), (float)(W0 - 1));
    of2[idx] = bsample(of0 + (size_t)b * H0 * W0 * CADJ, H0, W0, CADJ, c, sx, sy);
}

// ---- sampling + z-fuse v7 (measured best): bf16 gathers, single-prior loop ----
__global__ __launch_bounds__(256) void k_sample(
    const float* __restrict__ priors,
    const __hip_bfloat16* __restrict__ feats0, const __hip_bfloat16* __restrict__ feats1,
    const __hip_bfloat16* __restrict__ feats2,
    const float* __restrict__ offs0,  const float* __restrict__ offs1,  const float* __restrict__ offs2,
    const float* __restrict__ z_emb,
    __hip_bfloat16* __restrict__ fsout)
{
    const int bid = blockIdx.x;                    // 3072
    const int gi = (bid & 7) * 384 + (bid >> 3);   // XCD x owns batch x
    const int bp0 = gi * 2;
    const int b = bp0 / PP;
    const int tid = threadIdx.x;

    __shared__ __align__(16) int   ib[2][3][SS][4];
    __shared__ __align__(16) float wz[2][3][SS][4];

    const int Hs[3] = {H0, H1, H2};
    const int Wsz[3] = {W0, W1, W2};
    const __hip_bfloat16* Fb[3] = { feats0 + (size_t)b * H0 * W0 * CADJ,
                                    feats1 + (size_t)b * H1 * W1 * CADJ,
                                    feats2 + (size_t)b * H2 * W2 * CADJ };
    const float* Ob[3] = { offs0 + (size_t)b * H0 * W0 * CADJ,
                           offs1 + (size_t)b * H1 * W1 * CADJ,
                           offs2 + (size_t)b * H2 * W2 * CADJ };

    if (tid < 2 * 3 * SS) {
        const int p = tid / 108;
        const int l = (tid % 108) / SS;
        const int s = tid % SS;
        const int bp = bp0 + p;
        const float t = (float)(35 - s) / 35.0f;
        const int m = (int)floorf(t * 71.0f);
        const float pfx = priors[(size_t)bp * NPRI + 4 + m];
        const float gxv = fminf(fmaxf(pfx / 71.0f, 0.0f), 1.0f) * 2.0f - 1.0f;
        const float gyv = (1.0f - (float)m / 71.0f) * 2.0f - 1.0f;
        const float z = z_emb[s];
        const float e0 = expf(-0.5f * z * z);
        const float e1 = expf(-0.5f * (z - 1.0f) * (z - 1.0f));
        const float e2 = expf(-0.5f * (z - 2.0f) * (z - 2.0f));
        const float inv = 1.0f / (e0 + e1 + e2);
        const float ev[3] = {e0, e1, e2};
        const float zwl = ev[l] * inv;

        const int Hl = Hs[l], Wl = Wsz[l];
        const float px = (gxv + 1.0f) * 0.5f * (float)(Wl - 1);
        const float py = (gyv + 1.0f) * 0.5f * (float)(Hl - 1);
        const float dy = bsample(Ob[l], Hl, Wl, CADJ, 2 * s,     px, py);
        const float dx = bsample(Ob[l], Hl, Wl, CADJ, 2 * s + 1, px, py);
        const float sx = px + dx, sy = py + dy;
        const float x0f = floorf(sx), y0f = floorf(sy);
        const int x0 = (int)x0f, y0 = (int)y0f;
        const float wx1 = sx - x0f, wy1 = sy - y0f;
        const float wx0 = 1.0f - wx1, wy0 = 1.0f - wy1;
        const bool vx0 = (x0 >= 0) && (x0 < Wl);
        const bool vx1 = (x0 + 1 >= 0) && (x0 + 1 < Wl);
        const bool vy0 = (y0 >= 0) && (y0 < Hl);
        const bool vy1 = (y0 + 1 >= 0) && (y0 + 1 < Hl);
        const int xc0 = min(max(x0, 0), Wl - 1);
        const int xc1 = min(max(x0 + 1, 0), Wl - 1);
        const int yc0 = min(max(y0, 0), Hl - 1);
        const int yc1 = min(max(y0 + 1, 0), Hl - 1);
        wz[p][l][s][0] = ((vx0 && vy0) ? wx0 * wy0 : 0.0f) * zwl;
        wz[p][l][s][1] = ((vx1 && vy0) ? wx1 * wy0 : 0.0f) * zwl;
        wz[p][l][s][2] = ((vx0 && vy1) ? wx0 * wy1 : 0.0f) * zwl;
        wz[p][l][s][3] = ((vx1 && vy1) ? wx1 * wy1 : 0.0f) * zwl;
        ib[p][l][s][0] = (yc0 * Wl + xc0) * CADJ;
        ib[p][l][s][1] = (yc0 * Wl + xc1) * CADJ;
        ib[p][l][s][2] = (yc1 * Wl + xc0) * CADJ;
        ib[p][l][s][3] = (yc1 * Wl + xc1) * CADJ;
    }
    __syncthreads();

    for (int idx = tid; idx < 2 * SS * 18; idx += 256) {
        const int p = idx / 648;
        const int rem = idx % 648;
        const int s = rem / 18, k4 = (rem % 18) * 4;
        float a0 = 0.f, a1 = 0.f, a2 = 0.f, a3 = 0.f;
#pragma unroll
        for (int l = 0; l < 3; ++l) {
            const __hip_bfloat16* F = Fb[l];
            const int4   i4 = *(const int4*)&ib[p][l][s][0];
            const float4 w4 = *(const float4*)&wz[p][l][s][0];
            const bf16x4 v0 = *(const bf16x4*)(F + i4.x + k4);
            const bf16x4 v1 = *(const bf16x4*)(F + i4.y + k4);
            const bf16x4 v2 = *(const bf16x4*)(F + i4.z + k4);
            const bf16x4 v3 = *(const bf16x4*)(F + i4.w + k4);
            a0 = fmaf(w4.x, bfs2f(v0[0]), a0); a1 = fmaf(w4.x, bfs2f(v0[1]), a1);
            a2 = fmaf(w4.x, bfs2f(v0[2]), a2); a3 = fmaf(w4.x, bfs2f(v0[3]), a3);
            a0 = fmaf(w4.y, bfs2f(v1[0]), a0); a1 = fmaf(w4.y, bfs2f(v1[1]), a1);
            a2 = fmaf(w4.y, bfs2f(v1[2]), a2); a3 = fmaf(w4.y, bfs2f(v1[3]), a3);
            a0 = fmaf(w4.z, bfs2f(v2[0]), a0); a1 = fmaf(w4.z, bfs2f(v2[1]), a1);
            a2 = fmaf(w4.z, bfs2f(v2[2]), a2); a3 = fmaf(w4.z, bfs2f(v2[3]), a3);
            a0 = fmaf(w4.w, bfs2f(v3[0]), a0); a1 = fmaf(w4.w, bfs2f(v3[1]), a1);
            a2 = fmaf(w4.w, bfs2f(v3[2]), a2); a3 = fmaf(w4.w, bfs2f(v3[3]), a3);
        }
        bf16x4 pk;
        pk[0] = to_bf16s(a0); pk[1] = to_bf16s(a1);
        pk[2] = to_bf16s(a2); pk[3] = to_bf16s(a3);
        __hip_bfloat16* orow = fsout + (size_t)(bp0 + p) * 2688;
        *(bf16x4*)&orow[(s / 9) * 672 + (s % 9) * 72 + k4] = pk;
    }
    if (tid < 2 * 96) {
        const int p = tid / 96, g = (tid % 96) / 24, t = tid % 24;
        fsout[(size_t)(bp0 + p) * 2688 + g * 672 + 648 + t] = to_bf16(0.0f);
    }
}

// ---- bf16 MFMA GEMM, 128x128 tile, DOUBLE-BUFFERED global_load_lds (QKV) ----
__global__ __launch_bounds__(256) void k_bgemm(
    const __hip_bfloat16* __restrict__ A, int lda, long sAz,
    const __hip_bfloat16* __restrict__ W, int ldw, long sWz,
    const float* __restrict__ bias, int sBz,
    const __hip_bfloat16* __restrict__ Res, int ldres,
    __hip_bfloat16* __restrict__ C, int ldc, int sCz,
    int K, int relu)
{
    __shared__ __hip_bfloat16 As[2][128][32];
    __shared__ __hip_bfloat16 Bs[2][128][32];
    const int tid = threadIdx.x;
    const int lane = tid & 63, w = tid >> 6;
    const int wr = w >> 1, wc = w & 1;
    const int row16 = lane & 15, kg = lane >> 4;
    const int z = blockIdx.z;
    const int m0 = blockIdx.y * 128, n0 = blockIdx.x * 128;
    const __hip_bfloat16* Ab = A + (size_t)z * sAz;
    const __hip_bfloat16* Wb = W + (size_t)z * sWz;
    const int gr = lane >> 2;
    const int gc = (lane & 3) * 8;

#define STAGE128(buf, kbase)                                                       \
    {                                                                              \
        _Pragma("unroll")                                                          \
        for (int c = 0; c < 2; ++c) {                                              \
            const int r = w * 32 + c * 16;                                         \
            __builtin_amdgcn_global_load_lds(                                      \
                (gas_t)(Ab + (size_t)(m0 + r + gr) * lda + (kbase) + gc),          \
                (las_t)&As[buf][r][0], 16, 0, 0);                                  \
            __builtin_amdgcn_global_load_lds(                                      \
                (gas_t)(Wb + (size_t)(n0 + r + gr) * ldw + (kbase) + gc),          \
                (las_t)&Bs[buf][r][0], 16, 0, 0);                                  \
        }                                                                          \
    }

    f32x4 acc[4][4];
#pragma unroll
    for (int i = 0; i < 4; ++i)
#pragma unroll
        for (int j = 0; j < 4; ++j) acc[i][j] = (f32x4){0.f, 0.f, 0.f, 0.f};

    STAGE128(0, 0)
    __syncthreads();

    int cur = 0;
    for (int k0 = 0; k0 < K; k0 += 32) {
        if (k0 + 32 < K) STAGE128(cur ^ 1, k0 + 32)
        bf16x8 af[4], bfr[4];
#pragma unroll
        for (int i = 0; i < 4; ++i) af[i]  = *(const bf16x8*)&As[cur][wr * 64 + i * 16 + row16][kg * 8];
#pragma unroll
        for (int j = 0; j < 4; ++j) bfr[j] = *(const bf16x8*)&Bs[cur][wc * 64 + j * 16 + row16][kg * 8];
#pragma unroll
        for (int i = 0; i < 4; ++i)
#pragma unroll
            for (int j = 0; j < 4; ++j)
                acc[i][j] = MFMA_BF16(af[i], bfr[j], acc[i][j], 0, 0, 0);
        __syncthreads();
        cur ^= 1;
    }
#undef STAGE128

    const float* bz = bias + (size_t)z * sBz;
    __hip_bfloat16* Cz = C + (size_t)z * sCz;
#pragma unroll
    for (int i = 0; i < 4; ++i) {
#pragma unroll
        for (int r = 0; r < 4; ++r) {
            const int row = m0 + wr * 64 + i * 16 + kg * 4 + r;
#pragma unroll
            for (int j = 0; j < 4; ++j) {
                const int col = n0 + wc * 64 + j * 16 + row16;
                float v = acc[i][j][r] + bz[col];
                if (Res) v += bf2f(Res[(size_t)row * ldres + col]);
                if (relu) v = fmaxf(v, 0.0f);
                Cz[(size_t)row * ldc + col] = to_bf16(v);
            }
        }
    }
}

// ---- bf16 MFMA GEMM, 64x64 tile, double-buffered LDS, K_STEP=32 ----
__global__ __launch_bounds__(256) void k_bgemm64(
    const __hip_bfloat16* __restrict__ A, int lda, long sAz,
    const __hip_bfloat16* __restrict__ W, int ldw, long sWz,
    const float* __restrict__ bias, int sBz,
    const __hip_bfloat16* __restrict__ Res, int ldres,
    __hip_bfloat16* __restrict__ C, int ldc, int sCz,
    int K, int relu)
{
    __shared__ __hip_bfloat16 As[2][64][32];
    __shared__ __hip_bfloat16 Bs[2][64][32];
    const int tid = threadIdx.x;
    const int lane = tid & 63, w = tid >> 6;
    const int wr = w >> 1, wc = w & 1;
    const int row16 = lane & 15, kg = lane >> 4;
    const int z = blockIdx.z;
    const int m0 = blockIdx.y * 64, n0 = blockIdx.x * 64;
    const __hip_bfloat16* Ab = A + (size_t)z * sAz;
    const __hip_bfloat16* Wb = W + (size_t)z * sWz;
    const int gr = lane >> 2;
    const int gc = (lane & 3) * 8;

    f32x4 acc[2][2];
#pragma unroll
    for (int i = 0; i < 2; ++i)
#pragma unroll
        for (int j = 0; j < 2; ++j) acc[i][j] = (f32x4){0.f, 0.f, 0.f, 0.f};

    __builtin_amdgcn_global_load_lds(
        (gas_t)(Ab + (size_t)(m0 + w * 16 + gr) * lda + gc),
        (las_t)&As[0][w * 16][0], 16, 0, 0);
    __builtin_amdgcn_global_load_lds(
        (gas_t)(Wb + (size_t)(n0 + w * 16 + gr) * ldw + gc),
        (las_t)&Bs[0][w * 16][0], 16, 0, 0);
    __syncthreads();

    int cur = 0;
    for (int k0 = 0; k0 < K; k0 += 32) {
        if (k0 + 32 < K) {
            const int nxt = cur ^ 1;
            __builtin_amdgcn_global_load_lds(
                (gas_t)(Ab + (size_t)(m0 + w * 16 + gr) * lda + k0 + 32 + gc),
                (las_t)&As[nxt][w * 16][0], 16, 0, 0);
            __builtin_amdgcn_global_load_lds(
                (gas_t)(Wb + (size_t)(n0 + w * 16 + gr) * ldw + k0 + 32 + gc),
                (las_t)&Bs[nxt][w * 16][0], 16, 0, 0);
        }
        bf16x8 af[2], bfr[2];
#pragma unroll
        for (int i = 0; i < 2; ++i) af[i]  = *(const bf16x8*)&As[cur][wr * 32 + i * 16 + row16][kg * 8];
#pragma unroll
        for (int j = 0; j < 2; ++j) bfr[j] = *(const bf16x8*)&Bs[cur][wc * 32 + j * 16 + row16][kg * 8];
#pragma unroll
        for (int i = 0; i < 2; ++i)
#pragma unroll
            for (int j = 0; j < 2; ++j)
                acc[i][j] = MFMA_BF16(af[i], bfr[j], acc[i][j], 0, 0, 0);
        __syncthreads();
        cur ^= 1;
    }

    const float* bz = bias + (size_t)z * sBz;
    __hip_bfloat16* Cz = C + (size_t)z * sCz;
#pragma unroll
    for (int i = 0; i < 2; ++i) {
#pragma unroll
        for (int r = 0; r < 4; ++r) {
            const int row = m0 + wr * 32 + i * 16 + kg * 4 + r;
#pragma unroll
            for (int j = 0; j < 2; ++j) {
                const int col = n0 + wc * 32 + j * 16 + row16;
                float v = acc[i][j][r] + bz[col];
                if (Res) v += bf2f(Res[(size_t)row * ldres + col]);
                if (relu) v = fmaxf(v, 0.0f);
                Cz[(size_t)row * ldc + col] = to_bf16(v);
            }
        }
    }
}

// ---- V transpose: qkv V-part -> Vt[bg][128 d][768 keys] ----
__global__ __launch_bounds__(256) void k_vt(
    const __hip_bfloat16* __restrict__ qkv, __hip_bfloat16* __restrict__ Vt)
{
    const int kt = blockIdx.x;
    const int bg = blockIdx.y;
    const int b = bg >> 2, g = bg & 3;
    const int tid = threadIdx.x;
    __shared__ unsigned short Vs[64][130];

    const __hip_bfloat16* src = qkv + (size_t)(b * PP + kt * 64) * 1536 + 1024 + g * 128;
    for (int i = tid; i < 1024; i += 256) {
        const int row = i >> 4, ch = i & 15;
        *(bf16x8*)&Vs[row][ch * 8] = *(const bf16x8*)(src + (size_t)row * 1536 + ch * 8);
    }
    __syncthreads();
    __hip_bfloat16* dst = Vt + (size_t)bg * 128 * 768 + kt * 64;
    for (int i = tid; i < 1024; i += 256) {
        const int d = i >> 3, kc = i & 7;
        bf16x8 pk;
#pragma unroll
        for (int j = 0; j < 8; ++j) pk[j] = (short)Vs[kc * 8 + j][d];
        *(bf16x8*)(dst + (size_t)d * 768 + kc * 8) = pk;
    }
}

// ---- flash attention v3: 32 q-rows/block, 128 threads (2 waves), grid 768 ----
__global__ __launch_bounds__(128) void k_fattn(
    const __hip_bfloat16* __restrict__ qkv, const __hip_bfloat16* __restrict__ Vt,
    __hip_bfloat16* __restrict__ Out)
{
    const int id = blockIdx.x;                  // 768 = 8 xcd * (4 bg * 24 qt)
    const int xcd = id & 7, rest = id >> 3;     // rest 0..95
    const int bg = xcd * 4 + rest / 24;
    const int qt = rest % 24;
    const int b = bg >> 2, g = bg & 3;
    const int tid = threadIdx.x, lane = tid & 63, w = tid >> 6;  // w in {0,1}
    const int row16 = lane & 15, kg = lane >> 4;
    const int q0 = qt * 32;

    __shared__ __hip_bfloat16 Klds[64][136];
    __shared__ __hip_bfloat16 Vtl[128][72];
    __shared__ __hip_bfloat16 Plds[2][16][72];

    const size_t rowQ = (size_t)(b * PP + q0 + w * 16 + row16) * 1536 + g * 128;
    bf16x8 aq[4];
#pragma unroll
    for (int t = 0; t < 4; ++t)
        aq[t] = *(const bf16x8*)(qkv + rowQ + t * 32 + kg * 8);

    f32x4 oacc[8];
#pragma unroll
    for (int dt = 0; dt < 8; ++dt) oacc[dt] = (f32x4){0.f, 0.f, 0.f, 0.f};
    float mrow[4] = {-3.0e38f, -3.0e38f, -3.0e38f, -3.0e38f};
    float lrow[4] = {0.f, 0.f, 0.f, 0.f};

    const __hip_bfloat16* Kb = qkv + (size_t)(b * PP) * 1536 + 512 + g * 128;
    const __hip_bfloat16* Vb = Vt + (size_t)bg * 128 * 768;
    const float sc = 0.08838834764831845f;

    // staging with 128 threads: K 64x128 (2 thr/row, 128B each), Vt 128x64 (1 thr/row)
    const int krow = tid >> 1, kch = tid & 1;   // kch*64 bf16 offset
    bf16x8 kreg[8], vreg[8];

    {
        const __hip_bfloat16* s1 = Kb + (size_t)krow * 1536 + kch * 64;
        const __hip_bfloat16* s2 = Vb + (size_t)tid * 768;
#pragma unroll
        for (int j = 0; j < 8; ++j) { kreg[j] = *(const bf16x8*)(s1 + j * 8);
                                      vreg[j] = *(const bf16x8*)(s2 + j * 8); }
    }

    for (int kt = 0; kt < 12; ++kt) {
        __syncthreads();
#pragma unroll
        for (int j = 0; j < 8; ++j) {
            *(bf16x8*)&Klds[krow][kch * 64 + j * 8] = kreg[j];
            *(bf16x8*)&Vtl[tid][j * 8] = vreg[j];
        }
        __syncthreads();
        if (kt < 11) {
            const __hip_bfloat16* s1 = Kb + (size_t)((kt + 1) * 64 + krow) * 1536 + kch * 64;
            const __hip_bfloat16* s2 = Vb + (size_t)tid * 768 + (kt + 1) * 64;
#pragma unroll
            for (int j = 0; j < 8; ++j) { kreg[j] = *(const bf16x8*)(s1 + j * 8);
                                          vreg[j] = *(const bf16x8*)(s2 + j * 8); }
        }

        f32x4 s4[4];
#pragma unroll
        for (int st = 0; st < 4; ++st) s4[st] = (f32x4){0.f, 0.f, 0.f, 0.f};
        __builtin_amdgcn_s_setprio(1);
#pragma unroll
        for (int st = 0; st < 4; ++st)
#pragma unroll
            for (int t = 0; t < 4; ++t)
                s4[st] = MFMA_BF16(aq[t],
                    *(const bf16x8*)&Klds[st * 16 + row16][t * 32 + kg * 8], s4[st], 0, 0, 0);
        __builtin_amdgcn_s_setprio(0);

        float pm[4];
#pragma unroll
        for (int r = 0; r < 4; ++r) {
            float m0 = fmaxf(fmaxf(s4[0][r], s4[1][r]), fmaxf(s4[2][r], s4[3][r])) * sc;
            m0 = fmaxf(m0, __shfl_xor(m0, 1));
            m0 = fmaxf(m0, __shfl_xor(m0, 2));
            m0 = fmaxf(m0, __shfl_xor(m0, 4));
            m0 = fmaxf(m0, __shfl_xor(m0, 8));
            pm[r] = m0;
        }
        const float need = fmaxf(fmaxf(pm[0] - mrow[0], pm[1] - mrow[1]),
                                 fmaxf(pm[2] - mrow[2], pm[3] - mrow[3]));
        if (!__all(need <= 8.0f)) {
#pragma unroll
            for (int r = 0; r < 4; ++r) {
                const float mn = fmaxf(mrow[r], pm[r]);
                const float so = __expf(mrow[r] - mn);
                lrow[r] *= so;
#pragma unroll
                for (int dt = 0; dt < 8; ++dt) oacc[dt][r] *= so;
                mrow[r] = mn;
            }
        }
#pragma unroll
        for (int r = 0; r < 4; ++r) {
            float rs = 0.f;
#pragma unroll
            for (int st = 0; st < 4; ++st) {
                const float p = __expf(s4[st][r] * sc - mrow[r]);
                rs += p;
                Plds[w][kg * 4 + r][st * 16 + row16] = to_bf16(p);
            }
            rs += __shfl_xor(rs, 1);
            rs += __shfl_xor(rs, 2);
            rs += __shfl_xor(rs, 4);
            rs += __shfl_xor(rs, 8);
            lrow[r] += rs;
        }

        __builtin_amdgcn_s_setprio(1);
#pragma unroll
        for (int ks = 0; ks < 2; ++ks) {
            bf16x8 ap = *(const bf16x8*)&Plds[w][row16][ks * 32 + kg * 8];
#pragma unroll
            for (int dt = 0; dt < 8; ++dt)
                oacc[dt] = MFMA_BF16(ap,
                    *(const bf16x8*)&Vtl[dt * 16 + row16][ks * 32 + kg * 8], oacc[dt], 0, 0, 0);
        }
        __builtin_amdgcn_s_setprio(0);
    }

    const size_t obase = (size_t)(b * PP + q0 + w * 16 + kg * 4) * DD + g * 128;
#pragma unroll
    for (int r = 0; r < 4; ++r) {
        const float inv = 1.0f / lrow[r];
#pragma unroll
        for (int dt = 0; dt < 8; ++dt)
            Out[obase + (size_t)r * DD + dt * 16 + row16] = to_bf16(oacc[dt][r] * inv);
    }
}

// ---- final heads: 4 rows per block (one wave each) ----
__global__ __launch_bounds__(256) void k_head(
    const __hip_bfloat16* __restrict__ clsreg, const __hip_bfloat16* __restrict__ ph,
    const float* __restrict__ cls_w2, const float* __restrict__ cls_b2,
    const float* __restrict__ p_w2, const float* __restrict__ p_b2,
    const float* __restrict__ b_scale, const float* __restrict__ b_bias,
    float* __restrict__ outp)
{
    const int bp = blockIdx.x * 4 + (threadIdx.x >> 6);
    const int lane = threadIdx.x & 63;
    const __hip_bfloat16* hr = clsreg + (size_t)bp * 1024;
    float a0 = 0.0f, a1 = 0.0f;
    for (int i = lane; i < DD; i += 64) {
        float h = bf2f(hr[i]);
        a0 = fmaf(h, cls_w2[i], a0);
        a1 = fmaf(h, cls_w2[DD + i], a1);
    }
    const __hip_bfloat16* pr = ph + (size_t)bp * 1024;
    float c0 = 0.0f, c1 = 0.0f, c2 = 0.0f, c3 = 0.0f;
    for (int i = lane; i < 1024; i += 64) {
        float h = bf2f(pr[i]);
        c0 = fmaf(h, p_w2[i], c0);
        c1 = fmaf(h, p_w2[1024 + i], c1);
        c2 = fmaf(h, p_w2[2048 + i], c2);
        c3 = fmaf(h, p_w2[3072 + i], c3);
    }
#pragma unroll
    for (int off = 32; off > 0; off >>= 1) {
        a0 += __shfl_down(a0, off);
        a1 += __shfl_down(a1, off);
        c0 += __shfl_down(c0, off);
        c1 += __shfl_down(c1, off);
        c2 += __shfl_down(c2, off);
        c3 += __shfl_down(c3, off);
    }
    a0 = __shfl(a0, 0); a1 = __shfl(a1, 0);
    c0 = __shfl(c0, 0); c1 = __shfl(c1, 0);
    c2 = __shfl(c2, 0); c3 = __shfl(c3, 0);
    const float k0 = c0 + p_b2[0];
    const float k1 = c1 + p_b2[1];
    const float scv = b_scale[0], biv = b_bias[0];
    const float k2 = (c2 + p_b2[2]) * scv + biv;
    const float k3 = (c3 + p_b2[3]) * scv + biv;
    float* orow = outp + (size_t)bp * 78;
    if (lane == 0) {
        orow[0] = a0 + cls_b2[0];
        orow[1] = a1 + cls_b2[1];
        orow[2] = k0; orow[3] = k1; orow[4] = k2; orow[5] = k3;
    }
    for (int o = lane; o < 72; o += 64) {
        float ys = (float)o / 71.0f;
        float tv = k0 + ys * (k1 + ys * (k2 + ys * k3));
        orow[6 + o] = 1.0f / (1.0f + expf(-tv));
    }
}

extern "C" void kernel_launch(void* const* d_in, const int* in_sizes, int n_in,
                              void* d_out, int out_size, void* d_ws, size_t ws_size,
                              hipStream_t stream)
{
    const float* feat0  = (const float*)d_in[0];
    const float* feat1  = (const float*)d_in[1];
    const float* feat2  = (const float*)d_in[2];
    const float* priors = (const float*)d_in[3];
    const float* ca_w   = (const float*)d_in[4];
    const float* ca_b   = (const float*)d_in[5];
    const float* off_w  = (const float*)d_in[6];
    const float* off_b  = (const float*)d_in[7];
    const float* dp_w   = (const float*)d_in[8];
    const float* dp_b   = (const float*)d_in[9];
    const float* z_emb  = (const float*)d_in[10];
    const float* gf_w   = (const float*)d_in[11];
    const float* gf_b   = (const float*)d_in[12];
    const float* wq     = (const float*)d_in[13];
    const float* bq     = (const float*)d_in[14];
    const float* wk     = (const float*)d_in[15];
    const float* bk     = (const float*)d_in[16];
    const float* wv     = (const float*)d_in[17];
    const float* bv     = (const float*)d_in[18];
    const float* wo     = (const float*)d_in[19];
    const float* bo     = (const float*)d_in[20];
    const float* cf_w1  = (const float*)d_in[21];
    const float* cf_b1  = (const float*)d_in[22];
    const float* cf_w2  = (const float*)d_in[23];
    const float* cf_b2  = (const float*)d_in[24];
    const float* cls_w1 = (const float*)d_in[25];
    const float* cls_b1 = (const float*)d_in[26];
    const float* cls_w2 = (const float*)d_in[27];
    const float* cls_b2 = (const float*)d_in[28];
    const float* reg_w1 = (const float*)d_in[29];
    const float* reg_b1 = (const float*)d_in[30];
    const float* p_w1   = (const float*)d_in[31];
    const float* p_b1   = (const float*)d_in[32];
    const float* p_w2   = (const float*)d_in[33];
    const float* p_b2   = (const float*)d_in[34];
    const float* b_scale = (const float*)d_in[35];
    const float* b_bias  = (const float*)d_in[36];
    float* out = (float*)d_out;

    char* wsb = (char*)d_ws;
    __hip_bfloat16* feature = (__hip_bfloat16*)(wsb + 0);          // [6144][512]
    __hip_bfloat16* qkvb    = (__hip_bfloat16*)(wsb + 6291456);    // [6144][1536]
    __hip_bfloat16* tb      = (__hip_bfloat16*)(wsb + 25165824);   // [6144][512]
    __hip_bfloat16* vtb     = (__hip_bfloat16*)(wsb + 31457280);   // Vt [32][128][768]
    __hip_bfloat16* rb      = (__hip_bfloat16*)(wsb + 31457280);   // wo out (after fattn)
    __hip_bfloat16* hb      = (__hip_bfloat16*)(wsb + 37748736);   // [6144][1024]
    __hip_bfloat16* f2      = (__hip_bfloat16*)(wsb + 50331648);   // [6144][512]
    __hip_bfloat16* clsregb = (__hip_bfloat16*)(wsb + 56623104);   // [6144][1024]
    __hip_bfloat16* phb     = (__hip_bfloat16*)(wsb + 69206016);   // [6144][1024]
    float* of1 = (float*)(wsb + 6291456);
    float* of2 = (float*)(wsb + 8595456);
    __hip_bfloat16* fe1 = (__hip_bfloat16*)(wsb + 9171456);
    __hip_bfloat16* fe2 = (__hip_bfloat16*)(wsb + 11475456);
    __hip_bfloat16* fsb = (__hip_bfloat16*)(wsb + 25165824);       // smp [6144][2688]
    __hip_bfloat16* fe0 = (__hip_bfloat16*)(wsb + 58195968);
    float* of0 = (float*)(wsb + 67411968);
    __hip_bfloat16* wqkv_bf   = (__hip_bfloat16*)(wsb + 81788928); // [1536][512]
    __hip_bfloat16* wo_bf     = (__hip_bfloat16*)(wsb + 83361792);
    __hip_bfloat16* cf1_bf    = (__hip_bfloat16*)(wsb + 83886080);
    __hip_bfloat16* cf2_bf    = (__hip_bfloat16*)(wsb + 84934656);
    __hip_bfloat16* clsreg_bf = (__hip_bfloat16*)(wsb + 85983232); // [1024][512]
    __hip_bfloat16* p1_bf     = (__hip_bfloat16*)(wsb + 87031808);
    __hip_bfloat16* gfw2_bf   = (__hip_bfloat16*)(wsb + 88080384); // [512][672]
    float* bqkv    = (float*)(wsb + 88768512);
    float* bclsreg = (float*)(wsb + 88774656);
    float* b2      = (float*)(wsb + 88778752);

    k_wprep<<<3587, 256, 0, stream>>>(
        wq, wk, wv, wo, cf_w1, cf_w2, cls_w1, reg_w1, p_w1, bq, bk, bv, cls_b1, reg_b1,
        gf_w, dp_w, dp_b, gf_b,
        wqkv_bf, wo_bf, cf1_bf, cf2_bf, clsreg_bf, p1_bf, gfw2_bf, b2, bqkv, bclsreg);

    k_adjoff<<<dim3(63, BB), 256, 0, stream>>>(feat0, ca_w, ca_b, off_w, off_b,
                                               fe0, of0, H0 * W0, 1);
    k_adjr12<<<160 + (BB * (H1 * W1 + H2 * W2) * CADJ + 255) / 256, 256, 0, stream>>>(
        feat1, feat2, ca_w, ca_b, fe1, fe2, of0, of1, of2);
    k_sample<<<3072, 256, 0, stream>>>(priors, fe0, fe1, fe2, of0, of1, of2, z_emb, fsb);

    const int M = BB * PP;
    k_bgemm64<<<dim3(2, M / 64, 4), 256, 0, stream>>>(
        fsb, 2688, 672, gfw2_bf, 672, 128 * 672, b2, 128,
        nullptr, 0, feature, DD, 128, 672, 0);
    k_bgemm<<<dim3(12, M / 128, 1), 256, 0, stream>>>(
        feature, DD, 0, wqkv_bf, DD, 0, bqkv, 0,
        nullptr, 0, qkvb, 1536, 0, DD, 0);
    k_vt<<<dim3(12, 32), 256, 0, stream>>>(qkvb, vtb);
    k_fattn<<<768, 128, 0, stream>>>(qkvb, vtb, tb);
    k_bgemm64<<<dim3(8, M / 64, 1), 256, 0, stream>>>(
        tb, DD, 0, wo_bf, DD, 0, bo, 0, nullptr, 0, rb, DD, 0, DD, 0);
    k_bgemm64<<<dim3(16, M / 64, 1), 256, 0, stream>>>(
        rb, DD, 0, cf1_bf, DD, 0, cf_b1, 0, nullptr, 0, hb, 1024, 0, DD, 1);
    k_bgemm64<<<dim3(8, M / 64, 1), 256, 0, stream>>>(
        hb, 1024, 0, cf2_bf, 1024, 0, cf_b2, 0, feature, DD, f2, DD, 0, 1024, 0);
    k_bgemm64<<<dim3(16, M / 64, 1), 256, 0, stream>>>(
        f2, DD, 0, clsreg_bf, DD, 0, bclsreg, 0, nullptr, 0, clsregb, 1024, 0, DD, 1);
    k_bgemm64<<<dim3(16, M / 64, 1), 256, 0, stream>>>(
        clsregb + 512, 1024, 0, p1_bf, DD, 0, p_b1, 0, nullptr, 0, phb, 1024, 0, DD, 1);

    k_head<<<M / 4, 256, 0, stream>>>(clsregb, phb, cls_w2, cls_b2, p_w2, p_b2, b_scale, b_bias, out);
}

// Round 16
// 282.787 us; speedup vs baseline: 1.0231x; 1.0231x over previous
//
#include <hip/hip_runtime.h>
#include <hip/hip_bf16.h>
#include <math.h>

#define BB 8
#define PP 768
#define NPRI 76
#define SS 36
#define CIN 64
#define CADJ 72
#define DD 512

#define H0 40
#define W0 100
#define H1 20
#define W1 50
#define H2 10
#define W2 25

typedef __attribute__((ext_vector_type(8))) short bf16x8;
typedef __attribute__((ext_vector_type(4))) short bf16x4;
typedef __attribute__((ext_vector_type(4))) float f32x4;
#define MFMA_BF16 __builtin_amdgcn_mfma_f32_16x16x32_bf16

typedef const __attribute__((address_space(1))) unsigned int* gas_t;
typedef __attribute__((address_space(3))) unsigned int* las_t;

__device__ __forceinline__ __hip_bfloat16 to_bf16(float v) { return __float2bfloat16(v); }
__device__ __forceinline__ float bf2f(__hip_bfloat16 v) { return __bfloat162float(v); }
__device__ __forceinline__ short to_bf16s(float v) {
    __hip_bfloat16 h = __float2bfloat16(v);
    return *reinterpret_cast<short*>(&h);
}
__device__ __forceinline__ float bfs2f(short s) {
    union { unsigned u; float f; } cv;
    cv.u = ((unsigned)(unsigned short)s) << 16;
    return cv.f;
}

// ---- bilinear sample, zeros outside (f32 source) ----
__device__ __forceinline__ float bsample(const float* __restrict__ img, int H, int W,
                                         int C, int c, float x, float y)
{
    float x0f = floorf(x), y0f = floorf(y);
    int x0 = (int)x0f, y0 = (int)y0f;
    float wx1 = x - x0f, wy1 = y - y0f;
    float wx0 = 1.0f - wx1, wy0 = 1.0f - wy1;
    int xc0 = min(max(x0, 0), W - 1);
    int xc1 = min(max(x0 + 1, 0), W - 1);
    int yc0 = min(max(y0, 0), H - 1);
    int yc1 = min(max(y0 + 1, 0), H - 1);
    bool vx0 = (x0 >= 0) && (x0 < W);
    bool vx1 = (x0 + 1 >= 0) && (x0 + 1 < W);
    bool vy0 = (y0 >= 0) && (y0 < H);
    bool vy1 = (y0 + 1 >= 0) && (y0 + 1 < H);
    float w00 = (vx0 && vy0) ? wx0 * wy0 : 0.0f;
    float w01 = (vx1 && vy0) ? wx1 * wy0 : 0.0f;
    float w10 = (vx0 && vy1) ? wx0 * wy1 : 0.0f;
    float w11 = (vx1 && vy1) ? wx1 * wy1 : 0.0f;
    return w00 * img[((size_t)yc0 * W + xc0) * C + c]
         + w01 * img[((size_t)yc0 * W + xc1) * C + c]
         + w10 * img[((size_t)yc1 * W + xc0) * C + c]
         + w11 * img[((size_t)yc1 * W + xc1) * C + c];
}

__device__ __forceinline__ void cast4(__hip_bfloat16* dst, const float* src, long i)
{
    const float4 v = *(const float4*)(src + i * 4);
    bf16x4 pk;
    pk[0] = to_bf16s(v.x); pk[1] = to_bf16s(v.y);
    pk[2] = to_bf16s(v.z); pk[3] = to_bf16s(v.w);
    *(bf16x4*)(dst + i * 4) = pk;
}

// ---- merged weight prep: wfuse | wfuseb | vec4 wcast | bias copy ----
__global__ __launch_bounds__(256) void k_wprep(
    const float* __restrict__ wq, const float* __restrict__ wk, const float* __restrict__ wv,
    const float* __restrict__ wo, const float* __restrict__ cf_w1, const float* __restrict__ cf_w2,
    const float* __restrict__ cls_w1, const float* __restrict__ reg_w1, const float* __restrict__ p_w1,
    const float* __restrict__ bq, const float* __restrict__ bk, const float* __restrict__ bv,
    const float* __restrict__ cls_b1, const float* __restrict__ reg_b1,
    const float* __restrict__ gf_w, const float* __restrict__ dp_w,
    const float* __restrict__ dp_b, const float* __restrict__ gf_b,
    __hip_bfloat16* __restrict__ wqkv, __hip_bfloat16* __restrict__ wo_bf,
    __hip_bfloat16* __restrict__ cf1_bf, __hip_bfloat16* __restrict__ cf2_bf,
    __hip_bfloat16* __restrict__ clsreg_bf, __hip_bfloat16* __restrict__ p1_bf,
    __hip_bfloat16* __restrict__ gfw2, float* __restrict__ b2,
    float* __restrict__ bqkv, float* __restrict__ bclsreg)
{
    __shared__ float dpS[CADJ][CADJ + 1];
    __shared__ float gfr[648];
    const int bid = blockIdx.x;
    const int tid = threadIdx.x;

    if (bid < 512) {
        const int o = bid;
        for (int i = tid; i < CADJ * CADJ; i += 256) dpS[i / CADJ][i % CADJ] = dp_w[i];
        for (int i = tid; i < 648; i += 256) gfr[i] = gf_w[(size_t)o * 648 + i];
        __syncthreads();
        for (int t = tid; t < 672; t += 256) {
            float acc = 0.0f;
            if (t < 648) {
                const int i = t / 72, m = t % 72;
                const float* gr = gfr + i * 72;
#pragma unroll 8
                for (int k = 0; k < 72; ++k) acc = fmaf(gr[k], dpS[k][m], acc);
            }
            gfw2[(size_t)o * 672 + t] = to_bf16(acc);
        }
        return;
    }
    if (bid < 514) {
        const int o = (bid - 512) * 256 + tid;
        if (o < DD) {
            const float* gr = gf_w + (size_t)o * 648;
            float acc = gf_b[o];
            for (int j = 0; j < 648; ++j) acc = fmaf(gr[j], dp_b[j % 72], acc);
            b2[o] = acc;
        }
        return;
    }
    if (bid < 3586) {
        long i = (long)(bid - 514) * 256 + tid;
        if (i < 65536) { cast4(wqkv, wq, i); return; }
        i -= 65536;
        if (i < 65536) { cast4(wqkv + 262144, wk, i); return; }
        i -= 65536;
        if (i < 65536) { cast4(wqkv + 524288, wv, i); return; }
        i -= 65536;
        if (i < 65536) { cast4(wo_bf, wo, i); return; }
        i -= 65536;
        if (i < 131072) { cast4(cf1_bf, cf_w1, i); return; }
        i -= 131072;
        if (i < 131072) { cast4(cf2_bf, cf_w2, i); return; }
        i -= 131072;
        if (i < 65536) { cast4(clsreg_bf, cls_w1, i); return; }
        i -= 65536;
        if (i < 65536) { cast4(clsreg_bf + 262144, reg_w1, i); return; }
        i -= 65536;
        if (i < 131072) { cast4(p1_bf, p_w1, i); return; }
        return;
    }
    for (int i = tid; i < 2560; i += 256) {
        if (i < 512) bqkv[i] = bq[i];
        else if (i < 1024) bqkv[i] = bk[i - 512];
        else if (i < 1536) bqkv[i] = bv[i - 1024];
        else if (i < 2048) bclsreg[i - 1536] = cls_b1[i - 1536];
        else bclsreg[i - 1536] = reg_b1[i - 2048];
    }
}

// ---- fused tiled channel-adjust (+ offset head), level 0, 64 pixels/block ----
__global__ __launch_bounds__(256) void k_adjoff(
    const float* __restrict__ f, const float* __restrict__ caw, const float* __restrict__ cab,
    const float* __restrict__ offw, const float* __restrict__ offb,
    __hip_bfloat16* __restrict__ feout, float* __restrict__ offout, int HW, int do_off)
{
    __shared__ float inS[64][65];
    __shared__ float wS[72][64];
    __shared__ float owS[72][73];
    __shared__ float feS[64][73];
    __shared__ float cabS[72], obS[72];

    const int tid = threadIdx.x;
    const int b = blockIdx.y;
    const int pix0 = blockIdx.x * 64;
    const int cnt = min(64, HW - pix0);
    const int px = tid & 63, og = tid >> 6, o0 = og * 18;

    const float* fb = f + (size_t)b * CIN * HW + pix0;
    for (int i = tid; i < 72 * 64; i += 256) wS[i >> 6][i & 63] = caw[i];
    if (do_off)
        for (int i = tid; i < 72 * 72; i += 256) owS[i / 72][i % 72] = offw[i];
    if (tid < 72) { cabS[tid] = cab[tid]; obS[tid] = do_off ? offb[tid] : 0.f; }
    for (int i = tid; i < 64 * 64; i += 256) {
        const int c = i >> 6, p = i & 63;
        inS[c][p] = (p < cnt) ? fb[(size_t)c * HW + p] : 0.f;
    }
    __syncthreads();

    float acc[18];
#pragma unroll
    for (int j = 0; j < 18; ++j) acc[j] = cabS[o0 + j];
#pragma unroll 4
    for (int c = 0; c < 64; ++c) {
        const float v = inS[c][px];
#pragma unroll
        for (int j = 0; j < 18; ++j) acc[j] = fmaf(v, wS[o0 + j][c], acc[j]);
    }
#pragma unroll
    for (int j = 0; j < 18; ++j) feS[px][o0 + j] = acc[j];
    __syncthreads();

    __hip_bfloat16* feg = feout + ((size_t)b * HW + pix0) * CADJ;
    for (int i = tid; i < cnt * CADJ; i += 256) feg[i] = to_bf16(feS[i / CADJ][i % CADJ]);

    if (!do_off) return;

    float acc2[18];
#pragma unroll
    for (int j = 0; j < 18; ++j) acc2[j] = obS[o0 + j];
#pragma unroll 4
    for (int c = 0; c < 72; ++c) {
        const float v = feS[px][c];
#pragma unroll
        for (int j = 0; j < 18; ++j) acc2[j] = fmaf(v, owS[o0 + j][c], acc2[j]);
    }
    __syncthreads();
#pragma unroll
    for (int j = 0; j < 18; ++j) feS[px][o0 + j] = acc2[j];
    __syncthreads();
    float* ofg = offout + ((size_t)b * HW + pix0) * CADJ;
    for (int i = tid; i < cnt * CADJ; i += 256) ofg[i] = feS[i / CADJ][i % CADJ];
}

// ---- merged: channel-adjust L1+L2 (blocks 0..159) | resize L1+L2 (rest) ----
__global__ __launch_bounds__(256) void k_adjr12(
    const float* __restrict__ f1, const float* __restrict__ f2,
    const float* __restrict__ caw, const float* __restrict__ cab,
    __hip_bfloat16* __restrict__ fe1, __hip_bfloat16* __restrict__ fe2,
    const float* __restrict__ of0, float* __restrict__ of1, float* __restrict__ of2)
{
    const int blk = blockIdx.x;
    const int tid = threadIdx.x;

    if (blk < 160) {
        __shared__ float inS[64][65];
        __shared__ float wS[72][64];
        __shared__ float feS[64][73];
        __shared__ float cabS[72];

        const int bx = blk % 20;
        const int b = blk / 20;
        const float* f;
        __hip_bfloat16* fe;
        int HW, pix0;
        if (bx < 16) { f = f1; fe = fe1; HW = H1 * W1; pix0 = bx * 64; }
        else         { f = f2; fe = fe2; HW = H2 * W2; pix0 = (bx - 16) * 64; }
        const int cnt = min(64, HW - pix0);
        const int px = tid & 63, og = tid >> 6, o0 = og * 18;

        const float* fb = f + (size_t)b * CIN * HW + pix0;
        for (int i = tid; i < 72 * 64; i += 256) wS[i >> 6][i & 63] = caw[i];
        if (tid < 72) cabS[tid] = cab[tid];
        for (int i = tid; i < 64 * 64; i += 256) {
            const int c = i >> 6, p = i & 63;
            inS[c][p] = (p < cnt) ? fb[(size_t)c * HW + p] : 0.f;
        }
        __syncthreads();

        float acc[18];
#pragma unroll
        for (int j = 0; j < 18; ++j) acc[j] = cabS[o0 + j];
#pragma unroll 4
        for (int c = 0; c < 64; ++c) {
            const float v = inS[c][px];
#pragma unroll
            for (int j = 0; j < 18; ++j) acc[j] = fmaf(v, wS[o0 + j][c], acc[j]);
        }
#pragma unroll
        for (int j = 0; j < 18; ++j) feS[px][o0 + j] = acc[j];
        __syncthreads();

        __hip_bfloat16* feg = fe + ((size_t)b * HW + pix0) * CADJ;
        for (int i = tid; i < cnt * CADJ; i += 256) feg[i] = to_bf16(feS[i / CADJ][i % CADJ]);
        return;
    }

    const int T1 = BB * H1 * W1 * CADJ;
    const int T2 = BB * H2 * W2 * CADJ;
    int idx = (blk - 160) * 256 + tid;
    if (idx < T1) {
        const int c = idx % CADJ;
        const int j = (idx / CADJ) % W1;
        const int i = (idx / (CADJ * W1)) % H1;
        const int b = idx / (CADJ * W1 * H1);
        float sy = fminf((float)i * ((float)(H0 - 1) / (float)(H1 - 1)), (float)(H0 - 1));
        float sx = fminf((float)j * ((float)(W0 - 1) / (float)(W1 - 1)), (float)(W0 - 1));
        of1[idx] = bsample(of0 + (size_t)b * H0 * W0 * CADJ, H0, W0, CADJ, c, sx, sy);
        return;
    }
    idx -= T1;
    if (idx >= T2) return;
    const int c = idx % CADJ;
    const int j = (idx / CADJ) % W2;
    const int i = (idx / (CADJ * W2)) % H2;
    const int b = idx / (CADJ * W2 * H2);
    float sy = fminf((float)i * ((float)(H0 - 1) / (float)(H2 - 1)), (float)(H0 - 1));
    float sx = fminf((float)j * ((float)(W0 - 1) / (float)(W2 - 1)), (float)(W0 - 1));
    of2[idx] = bsample(of0 + (size_t)b * H0 * W0 * CADJ, H0, W0, CADJ, c, sx, sy);
}

// ---- sampling + z-fuse v7 (measured best): bf16 gathers, single-prior loop ----
__global__ __launch_bounds__(256) void k_sample(
    const float* __restrict__ priors,
    const __hip_bfloat16* __restrict__ feats0, const __hip_bfloat16* __restrict__ feats1,
    const __hip_bfloat16* __restrict__ feats2,
    const float* __restrict__ offs0,  const float* __restrict__ offs1,  const float* __restrict__ offs2,
    const float* __restrict__ z_emb,
    __hip_bfloat16* __restrict__ fsout)
{
    const int bid = blockIdx.x;                    // 3072
    const int gi = (bid & 7) * 384 + (bid >> 3);   // XCD x owns batch x
    const int bp0 = gi * 2;
    const int b = bp0 / PP;
    const int tid = threadIdx.x;

    __shared__ __align__(16) int   ib[2][3][SS][4];
    __shared__ __align__(16) float wz[2][3][SS][4];

    const int Hs[3] = {H0, H1, H2};
    const int Wsz[3] = {W0, W1, W2};
    const __hip_bfloat16* Fb[3] = { feats0 + (size_t)b * H0 * W0 * CADJ,
                                    feats1 + (size_t)b * H1 * W1 * CADJ,
                                    feats2 + (size_t)b * H2 * W2 * CADJ };
    const float* Ob[3] = { offs0 + (size_t)b * H0 * W0 * CADJ,
                           offs1 + (size_t)b * H1 * W1 * CADJ,
                           offs2 + (size_t)b * H2 * W2 * CADJ };

    if (tid < 2 * 3 * SS) {
        const int p = tid / 108;
        const int l = (tid % 108) / SS;
        const int s = tid % SS;
        const int bp = bp0 + p;
        const float t = (float)(35 - s) / 35.0f;
        const int m = (int)floorf(t * 71.0f);
        const float pfx = priors[(size_t)bp * NPRI + 4 + m];
        const float gxv = fminf(fmaxf(pfx / 71.0f, 0.0f), 1.0f) * 2.0f - 1.0f;
        const float gyv = (1.0f - (float)m / 71.0f) * 2.0f - 1.0f;
        const float z = z_emb[s];
        const float e0 = expf(-0.5f * z * z);
        const float e1 = expf(-0.5f * (z - 1.0f) * (z - 1.0f));
        const float e2 = expf(-0.5f * (z - 2.0f) * (z - 2.0f));
        const float inv = 1.0f / (e0 + e1 + e2);
        const float ev[3] = {e0, e1, e2};
        const float zwl = ev[l] * inv;

        const int Hl = Hs[l], Wl = Wsz[l];
        const float px = (gxv + 1.0f) * 0.5f * (float)(Wl - 1);
        const float py = (gyv + 1.0f) * 0.5f * (float)(Hl - 1);
        const float dy = bsample(Ob[l], Hl, Wl, CADJ, 2 * s,     px, py);
        const float dx = bsample(Ob[l], Hl, Wl, CADJ, 2 * s + 1, px, py);
        const float sx = px + dx, sy = py + dy;
        const float x0f = floorf(sx), y0f = floorf(sy);
        const int x0 = (int)x0f, y0 = (int)y0f;
        const float wx1 = sx - x0f, wy1 = sy - y0f;
        const float wx0 = 1.0f - wx1, wy0 = 1.0f - wy1;
        const bool vx0 = (x0 >= 0) && (x0 < Wl);
        const bool vx1 = (x0 + 1 >= 0) && (x0 + 1 < Wl);
        const bool vy0 = (y0 >= 0) && (y0 < Hl);
        const bool vy1 = (y0 + 1 >= 0) && (y0 + 1 < Hl);
        const int xc0 = min(max(x0, 0), Wl - 1);
        const int xc1 = min(max(x0 + 1, 0), Wl - 1);
        const int yc0 = min(max(y0, 0), Hl - 1);
        const int yc1 = min(max(y0 + 1, 0), Hl - 1);
        wz[p][l][s][0] = ((vx0 && vy0) ? wx0 * wy0 : 0.0f) * zwl;
        wz[p][l][s][1] = ((vx1 && vy0) ? wx1 * wy0 : 0.0f) * zwl;
        wz[p][l][s][2] = ((vx0 && vy1) ? wx0 * wy1 : 0.0f) * zwl;
        wz[p][l][s][3] = ((vx1 && vy1) ? wx1 * wy1 : 0.0f) * zwl;
        ib[p][l][s][0] = (yc0 * Wl + xc0) * CADJ;
        ib[p][l][s][1] = (yc0 * Wl + xc1) * CADJ;
        ib[p][l][s][2] = (yc1 * Wl + xc0) * CADJ;
        ib[p][l][s][3] = (yc1 * Wl + xc1) * CADJ;
    }
    __syncthreads();

    for (int idx = tid; idx < 2 * SS * 18; idx += 256) {
        const int p = idx / 648;
        const int rem = idx % 648;
        const int s = rem / 18, k4 = (rem % 18) * 4;
        float a0 = 0.f, a1 = 0.f, a2 = 0.f, a3 = 0.f;
#pragma unroll
        for (int l = 0; l < 3; ++l) {
            const __hip_bfloat16* F = Fb[l];
            const int4   i4 = *(const int4*)&ib[p][l][s][0];
            const float4 w4 = *(const float4*)&wz[p][l][s][0];
            const bf16x4 v0 = *(const bf16x4*)(F + i4.x + k4);
            const bf16x4 v1 = *(const bf16x4*)(F + i4.y + k4);
            const bf16x4 v2 = *(const bf16x4*)(F + i4.z + k4);
            const bf16x4 v3 = *(const bf16x4*)(F + i4.w + k4);
            a0 = fmaf(w4.x, bfs2f(v0[0]), a0); a1 = fmaf(w4.x, bfs2f(v0[1]), a1);
            a2 = fmaf(w4.x, bfs2f(v0[2]), a2); a3 = fmaf(w4.x, bfs2f(v0[3]), a3);
            a0 = fmaf(w4.y, bfs2f(v1[0]), a0); a1 = fmaf(w4.y, bfs2f(v1[1]), a1);
            a2 = fmaf(w4.y, bfs2f(v1[2]), a2); a3 = fmaf(w4.y, bfs2f(v1[3]), a3);
            a0 = fmaf(w4.z, bfs2f(v2[0]), a0); a1 = fmaf(w4.z, bfs2f(v2[1]), a1);
            a2 = fmaf(w4.z, bfs2f(v2[2]), a2); a3 = fmaf(w4.z, bfs2f(v2[3]), a3);
            a0 = fmaf(w4.w, bfs2f(v3[0]), a0); a1 = fmaf(w4.w, bfs2f(v3[1]), a1);
            a2 = fmaf(w4.w, bfs2f(v3[2]), a2); a3 = fmaf(w4.w, bfs2f(v3[3]), a3);
        }
        bf16x4 pk;
        pk[0] = to_bf16s(a0); pk[1] = to_bf16s(a1);
        pk[2] = to_bf16s(a2); pk[3] = to_bf16s(a3);
        __hip_bfloat16* orow = fsout + (size_t)(bp0 + p) * 2688;
        *(bf16x4*)&orow[(s / 9) * 672 + (s % 9) * 72 + k4] = pk;
    }
    if (tid < 2 * 96) {
        const int p = tid / 96, g = (tid % 96) / 24, t = tid % 24;
        fsout[(size_t)(bp0 + p) * 2688 + g * 672 + 648 + t] = to_bf16(0.0f);
    }
}

// ---- bf16 MFMA GEMM, 128x128 tile, DOUBLE-BUFFERED global_load_lds (QKV) ----
__global__ __launch_bounds__(256) void k_bgemm(
    const __hip_bfloat16* __restrict__ A, int lda, long sAz,
    const __hip_bfloat16* __restrict__ W, int ldw, long sWz,
    const float* __restrict__ bias, int sBz,
    const __hip_bfloat16* __restrict__ Res, int ldres,
    __hip_bfloat16* __restrict__ C, int ldc, int sCz,
    int K, int relu)
{
    __shared__ __hip_bfloat16 As[2][128][32];
    __shared__ __hip_bfloat16 Bs[2][128][32];
    const int tid = threadIdx.x;
    const int lane = tid & 63, w = tid >> 6;
    const int wr = w >> 1, wc = w & 1;
    const int row16 = lane & 15, kg = lane >> 4;
    const int z = blockIdx.z;
    const int m0 = blockIdx.y * 128, n0 = blockIdx.x * 128;
    const __hip_bfloat16* Ab = A + (size_t)z * sAz;
    const __hip_bfloat16* Wb = W + (size_t)z * sWz;
    const int gr = lane >> 2;
    const int gc = (lane & 3) * 8;

#define STAGE128(buf, kbase)                                                       \
    {                                                                              \
        _Pragma("unroll")                                                          \
        for (int c = 0; c < 2; ++c) {                                              \
            const int r = w * 32 + c * 16;                                         \
            __builtin_amdgcn_global_load_lds(                                      \
                (gas_t)(Ab + (size_t)(m0 + r + gr) * lda + (kbase) + gc),          \
                (las_t)&As[buf][r][0], 16, 0, 0);                                  \
            __builtin_amdgcn_global_load_lds(                                      \
                (gas_t)(Wb + (size_t)(n0 + r + gr) * ldw + (kbase) + gc),          \
                (las_t)&Bs[buf][r][0], 16, 0, 0);                                  \
        }                                                                          \
    }

    f32x4 acc[4][4];
#pragma unroll
    for (int i = 0; i < 4; ++i)
#pragma unroll
        for (int j = 0; j < 4; ++j) acc[i][j] = (f32x4){0.f, 0.f, 0.f, 0.f};

    STAGE128(0, 0)
    __syncthreads();

    int cur = 0;
    for (int k0 = 0; k0 < K; k0 += 32) {
        if (k0 + 32 < K) STAGE128(cur ^ 1, k0 + 32)
        bf16x8 af[4], bfr[4];
#pragma unroll
        for (int i = 0; i < 4; ++i) af[i]  = *(const bf16x8*)&As[cur][wr * 64 + i * 16 + row16][kg * 8];
#pragma unroll
        for (int j = 0; j < 4; ++j) bfr[j] = *(const bf16x8*)&Bs[cur][wc * 64 + j * 16 + row16][kg * 8];
#pragma unroll
        for (int i = 0; i < 4; ++i)
#pragma unroll
            for (int j = 0; j < 4; ++j)
                acc[i][j] = MFMA_BF16(af[i], bfr[j], acc[i][j], 0, 0, 0);
        __syncthreads();
        cur ^= 1;
    }
#undef STAGE128

    const float* bz = bias + (size_t)z * sBz;
    __hip_bfloat16* Cz = C + (size_t)z * sCz;
#pragma unroll
    for (int i = 0; i < 4; ++i) {
#pragma unroll
        for (int r = 0; r < 4; ++r) {
            const int row = m0 + wr * 64 + i * 16 + kg * 4 + r;
#pragma unroll
            for (int j = 0; j < 4; ++j) {
                const int col = n0 + wc * 64 + j * 16 + row16;
                float v = acc[i][j][r] + bz[col];
                if (Res) v += bf2f(Res[(size_t)row * ldres + col]);
                if (relu) v = fmaxf(v, 0.0f);
                Cz[(size_t)row * ldc + col] = to_bf16(v);
            }
        }
    }
}

// ---- bf16 MFMA GEMM, 64x64 tile, double-buffered LDS, K_STEP=32 ----
__global__ __launch_bounds__(256) void k_bgemm64(
    const __hip_bfloat16* __restrict__ A, int lda, long sAz,
    const __hip_bfloat16* __restrict__ W, int ldw, long sWz,
    const float* __restrict__ bias, int sBz,
    const __hip_bfloat16* __restrict__ Res, int ldres,
    __hip_bfloat16* __restrict__ C, int ldc, int sCz,
    int K, int relu)
{
    __shared__ __hip_bfloat16 As[2][64][32];
    __shared__ __hip_bfloat16 Bs[2][64][32];
    const int tid = threadIdx.x;
    const int lane = tid & 63, w = tid >> 6;
    const int wr = w >> 1, wc = w & 1;
    const int row16 = lane & 15, kg = lane >> 4;
    const int z = blockIdx.z;
    const int m0 = blockIdx.y * 64, n0 = blockIdx.x * 64;
    const __hip_bfloat16* Ab = A + (size_t)z * sAz;
    const __hip_bfloat16* Wb = W + (size_t)z * sWz;
    const int gr = lane >> 2;
    const int gc = (lane & 3) * 8;

    f32x4 acc[2][2];
#pragma unroll
    for (int i = 0; i < 2; ++i)
#pragma unroll
        for (int j = 0; j < 2; ++j) acc[i][j] = (f32x4){0.f, 0.f, 0.f, 0.f};

    __builtin_amdgcn_global_load_lds(
        (gas_t)(Ab + (size_t)(m0 + w * 16 + gr) * lda + gc),
        (las_t)&As[0][w * 16][0], 16, 0, 0);
    __builtin_amdgcn_global_load_lds(
        (gas_t)(Wb + (size_t)(n0 + w * 16 + gr) * ldw + gc),
        (las_t)&Bs[0][w * 16][0], 16, 0, 0);
    __syncthreads();

    int cur = 0;
    for (int k0 = 0; k0 < K; k0 += 32) {
        if (k0 + 32 < K) {
            const int nxt = cur ^ 1;
            __builtin_amdgcn_global_load_lds(
                (gas_t)(Ab + (size_t)(m0 + w * 16 + gr) * lda + k0 + 32 + gc),
                (las_t)&As[nxt][w * 16][0], 16, 0, 0);
            __builtin_amdgcn_global_load_lds(
                (gas_t)(Wb + (size_t)(n0 + w * 16 + gr) * ldw + k0 + 32 + gc),
                (las_t)&Bs[nxt][w * 16][0], 16, 0, 0);
        }
        bf16x8 af[2], bfr[2];
#pragma unroll
        for (int i = 0; i < 2; ++i) af[i]  = *(const bf16x8*)&As[cur][wr * 32 + i * 16 + row16][kg * 8];
#pragma unroll
        for (int j = 0; j < 2; ++j) bfr[j] = *(const bf16x8*)&Bs[cur][wc * 32 + j * 16 + row16][kg * 8];
#pragma unroll
        for (int i = 0; i < 2; ++i)
#pragma unroll
            for (int j = 0; j < 2; ++j)
                acc[i][j] = MFMA_BF16(af[i], bfr[j], acc[i][j], 0, 0, 0);
        __syncthreads();
        cur ^= 1;
    }

    const float* bz = bias + (size_t)z * sBz;
    __hip_bfloat16* Cz = C + (size_t)z * sCz;
#pragma unroll
    for (int i = 0; i < 2; ++i) {
#pragma unroll
        for (int r = 0; r < 4; ++r) {
            const int row = m0 + wr * 32 + i * 16 + kg * 4 + r;
#pragma unroll
            for (int j = 0; j < 2; ++j) {
                const int col = n0 + wc * 32 + j * 16 + row16;
                float v = acc[i][j][r] + bz[col];
                if (Res) v += bf2f(Res[(size_t)row * ldres + col]);
                if (relu) v = fmaxf(v, 0.0f);
                Cz[(size_t)row * ldc + col] = to_bf16(v);
            }
        }
    }
}

// ---- V transpose: qkv V-part -> Vt[bg][128 d][768 keys] ----
__global__ __launch_bounds__(256) void k_vt(
    const __hip_bfloat16* __restrict__ qkv, __hip_bfloat16* __restrict__ Vt)
{
    const int kt = blockIdx.x;
    const int bg = blockIdx.y;
    const int b = bg >> 2, g = bg & 3;
    const int tid = threadIdx.x;
    __shared__ unsigned short Vs[64][130];

    const __hip_bfloat16* src = qkv + (size_t)(b * PP + kt * 64) * 1536 + 1024 + g * 128;
    for (int i = tid; i < 1024; i += 256) {
        const int row = i >> 4, ch = i & 15;
        *(bf16x8*)&Vs[row][ch * 8] = *(const bf16x8*)(src + (size_t)row * 1536 + ch * 8);
    }
    __syncthreads();
    __hip_bfloat16* dst = Vt + (size_t)bg * 128 * 768 + kt * 64;
    for (int i = tid; i < 1024; i += 256) {
        const int d = i >> 3, kc = i & 7;
        bf16x8 pk;
#pragma unroll
        for (int j = 0; j < 8; ++j) pk[j] = (short)Vs[kc * 8 + j][d];
        *(bf16x8*)(dst + (size_t)d * 768 + kc * 8) = pk;
    }
}

// ---- flash attention v2 (measured best): 64 q-rows, 256 threads, grid 384 ----
__global__ __launch_bounds__(256) void k_fattn(
    const __hip_bfloat16* __restrict__ qkv, const __hip_bfloat16* __restrict__ Vt,
    __hip_bfloat16* __restrict__ Out)
{
    const int id = blockIdx.x;
    const int xcd = id & 7, rest = id >> 3;
    const int bg = xcd * 4 + rest / 12;
    const int qt = rest % 12;
    const int b = bg >> 2, g = bg & 3;
    const int tid = threadIdx.x, lane = tid & 63, w = tid >> 6;
    const int row16 = lane & 15, kg = lane >> 4;
    const int q0 = qt * 64;

    __shared__ __hip_bfloat16 Klds[64][136];
    __shared__ __hip_bfloat16 Vtl[128][72];
    __shared__ __hip_bfloat16 Plds[4][16][72];

    const size_t rowQ = (size_t)(b * PP + q0 + w * 16 + row16) * 1536 + g * 128;
    bf16x8 aq[4];
#pragma unroll
    for (int t = 0; t < 4; ++t)
        aq[t] = *(const bf16x8*)(qkv + rowQ + t * 32 + kg * 8);

    f32x4 oacc[8];
#pragma unroll
    for (int dt = 0; dt < 8; ++dt) oacc[dt] = (f32x4){0.f, 0.f, 0.f, 0.f};
    float mrow[4] = {-3.0e38f, -3.0e38f, -3.0e38f, -3.0e38f};
    float lrow[4] = {0.f, 0.f, 0.f, 0.f};

    const __hip_bfloat16* Kb = qkv + (size_t)(b * PP) * 1536 + 512 + g * 128;
    const __hip_bfloat16* Vb = Vt + (size_t)bg * 128 * 768;
    const float sc = 0.08838834764831845f;

    const int krow = tid >> 2, kch = tid & 3;
    const int vrow = tid >> 1, vch = tid & 1;
    bf16x8 kreg[4], vreg[4];

    {
        const __hip_bfloat16* s1 = Kb + (size_t)krow * 1536 + kch * 32;
        const __hip_bfloat16* s2 = Vb + (size_t)vrow * 768 + vch * 32;
#pragma unroll
        for (int j = 0; j < 4; ++j) { kreg[j] = *(const bf16x8*)(s1 + j * 8);
                                      vreg[j] = *(const bf16x8*)(s2 + j * 8); }
    }

    for (int kt = 0; kt < 12; ++kt) {
        __syncthreads();
#pragma unroll
        for (int j = 0; j < 4; ++j) {
            *(bf16x8*)&Klds[krow][kch * 32 + j * 8] = kreg[j];
            *(bf16x8*)&Vtl[vrow][vch * 32 + j * 8] = vreg[j];
        }
        __syncthreads();
        if (kt < 11) {
            const __hip_bfloat16* s1 = Kb + (size_t)((kt + 1) * 64 + krow) * 1536 + kch * 32;
            const __hip_bfloat16* s2 = Vb + (size_t)vrow * 768 + (kt + 1) * 64 + vch * 32;
#pragma unroll
            for (int j = 0; j < 4; ++j) { kreg[j] = *(const bf16x8*)(s1 + j * 8);
                                          vreg[j] = *(const bf16x8*)(s2 + j * 8); }
        }

        f32x4 s4[4];
#pragma unroll
        for (int st = 0; st < 4; ++st) s4[st] = (f32x4){0.f, 0.f, 0.f, 0.f};
        __builtin_amdgcn_s_setprio(1);
#pragma unroll
        for (int st = 0; st < 4; ++st)
#pragma unroll
            for (int t = 0; t < 4; ++t)
                s4[st] = MFMA_BF16(aq[t],
                    *(const bf16x8*)&Klds[st * 16 + row16][t * 32 + kg * 8], s4[st], 0, 0, 0);
        __builtin_amdgcn_s_setprio(0);

        float pm[4];
#pragma unroll
        for (int r = 0; r < 4; ++r) {
            float m0 = fmaxf(fmaxf(s4[0][r], s4[1][r]), fmaxf(s4[2][r], s4[3][r])) * sc;
            m0 = fmaxf(m0, __shfl_xor(m0, 1));
            m0 = fmaxf(m0, __shfl_xor(m0, 2));
            m0 = fmaxf(m0, __shfl_xor(m0, 4));
            m0 = fmaxf(m0, __shfl_xor(m0, 8));
            pm[r] = m0;
        }
        const float need = fmaxf(fmaxf(pm[0] - mrow[0], pm[1] - mrow[1]),
                                 fmaxf(pm[2] - mrow[2], pm[3] - mrow[3]));
        if (!__all(need <= 8.0f)) {
#pragma unroll
            for (int r = 0; r < 4; ++r) {
                const float mn = fmaxf(mrow[r], pm[r]);
                const float so = __expf(mrow[r] - mn);
                lrow[r] *= so;
#pragma unroll
                for (int dt = 0; dt < 8; ++dt) oacc[dt][r] *= so;
                mrow[r] = mn;
            }
        }
#pragma unroll
        for (int r = 0; r < 4; ++r) {
            float rs = 0.f;
#pragma unroll
            for (int st = 0; st < 4; ++st) {
                const float p = __expf(s4[st][r] * sc - mrow[r]);
                rs += p;
                Plds[w][kg * 4 + r][st * 16 + row16] = to_bf16(p);
            }
            rs += __shfl_xor(rs, 1);
            rs += __shfl_xor(rs, 2);
            rs += __shfl_xor(rs, 4);
            rs += __shfl_xor(rs, 8);
            lrow[r] += rs;
        }

        __builtin_amdgcn_s_setprio(1);
#pragma unroll
        for (int ks = 0; ks < 2; ++ks) {
            bf16x8 ap = *(const bf16x8*)&Plds[w][row16][ks * 32 + kg * 8];
#pragma unroll
            for (int dt = 0; dt < 8; ++dt)
                oacc[dt] = MFMA_BF16(ap,
                    *(const bf16x8*)&Vtl[dt * 16 + row16][ks * 32 + kg * 8], oacc[dt], 0, 0, 0);
        }
        __builtin_amdgcn_s_setprio(0);
    }

    const size_t obase = (size_t)(b * PP + q0 + w * 16 + kg * 4) * DD + g * 128;
#pragma unroll
    for (int r = 0; r < 4; ++r) {
        const float inv = 1.0f / lrow[r];
#pragma unroll
        for (int dt = 0; dt < 8; ++dt)
            Out[obase + (size_t)r * DD + dt * 16 + row16] = to_bf16(oacc[dt][r] * inv);
    }
}

// ---- final heads: 4 rows per block (one wave each) ----
__global__ __launch_bounds__(256) void k_head(
    const __hip_bfloat16* __restrict__ clsreg, const __hip_bfloat16* __restrict__ ph,
    const float* __restrict__ cls_w2, const float* __restrict__ cls_b2,
    const float* __restrict__ p_w2, const float* __restrict__ p_b2,
    const float* __restrict__ b_scale, const float* __restrict__ b_bias,
    float* __restrict__ outp)
{
    const int bp = blockIdx.x * 4 + (threadIdx.x >> 6);
    const int lane = threadIdx.x & 63;
    const __hip_bfloat16* hr = clsreg + (size_t)bp * 1024;
    float a0 = 0.0f, a1 = 0.0f;
    for (int i = lane; i < DD; i += 64) {
        float h = bf2f(hr[i]);
        a0 = fmaf(h, cls_w2[i], a0);
        a1 = fmaf(h, cls_w2[DD + i], a1);
    }
    const __hip_bfloat16* pr = ph + (size_t)bp * 1024;
    float c0 = 0.0f, c1 = 0.0f, c2 = 0.0f, c3 = 0.0f;
    for (int i = lane; i < 1024; i += 64) {
        float h = bf2f(pr[i]);
        c0 = fmaf(h, p_w2[i], c0);
        c1 = fmaf(h, p_w2[1024 + i], c1);
        c2 = fmaf(h, p_w2[2048 + i], c2);
        c3 = fmaf(h, p_w2[3072 + i], c3);
    }
#pragma unroll
    for (int off = 32; off > 0; off >>= 1) {
        a0 += __shfl_down(a0, off);
        a1 += __shfl_down(a1, off);
        c0 += __shfl_down(c0, off);
        c1 += __shfl_down(c1, off);
        c2 += __shfl_down(c2, off);
        c3 += __shfl_down(c3, off);
    }
    a0 = __shfl(a0, 0); a1 = __shfl(a1, 0);
    c0 = __shfl(c0, 0); c1 = __shfl(c1, 0);
    c2 = __shfl(c2, 0); c3 = __shfl(c3, 0);
    const float k0 = c0 + p_b2[0];
    const float k1 = c1 + p_b2[1];
    const float scv = b_scale[0], biv = b_bias[0];
    const float k2 = (c2 + p_b2[2]) * scv + biv;
    const float k3 = (c3 + p_b2[3]) * scv + biv;
    float* orow = outp + (size_t)bp * 78;
    if (lane == 0) {
        orow[0] = a0 + cls_b2[0];
        orow[1] = a1 + cls_b2[1];
        orow[2] = k0; orow[3] = k1; orow[4] = k2; orow[5] = k3;
    }
    for (int o = lane; o < 72; o += 64) {
        float ys = (float)o / 71.0f;
        float tv = k0 + ys * (k1 + ys * (k2 + ys * k3));
        orow[6 + o] = 1.0f / (1.0f + expf(-tv));
    }
}

extern "C" void kernel_launch(void* const* d_in, const int* in_sizes, int n_in,
                              void* d_out, int out_size, void* d_ws, size_t ws_size,
                              hipStream_t stream)
{
    const float* feat0  = (const float*)d_in[0];
    const float* feat1  = (const float*)d_in[1];
    const float* feat2  = (const float*)d_in[2];
    const float* priors = (const float*)d_in[3];
    const float* ca_w   = (const float*)d_in[4];
    const float* ca_b   = (const float*)d_in[5];
    const float* off_w  = (const float*)d_in[6];
    const float* off_b  = (const float*)d_in[7];
    const float* dp_w   = (const float*)d_in[8];
    const float* dp_b   = (const float*)d_in[9];
    const float* z_emb  = (const float*)d_in[10];
    const float* gf_w   = (const float*)d_in[11];
    const float* gf_b   = (const float*)d_in[12];
    const float* wq     = (const float*)d_in[13];
    const float* bq     = (const float*)d_in[14];
    const float* wk     = (const float*)d_in[15];
    const float* bk     = (const float*)d_in[16];
    const float* wv     = (const float*)d_in[17];
    const float* bv     = (const float*)d_in[18];
    const float* wo     = (const float*)d_in[19];
    const float* bo     = (const float*)d_in[20];
    const float* cf_w1  = (const float*)d_in[21];
    const float* cf_b1  = (const float*)d_in[22];
    const float* cf_w2  = (const float*)d_in[23];
    const float* cf_b2  = (const float*)d_in[24];
    const float* cls_w1 = (const float*)d_in[25];
    const float* cls_b1 = (const float*)d_in[26];
    const float* cls_w2 = (const float*)d_in[27];
    const float* cls_b2 = (const float*)d_in[28];
    const float* reg_w1 = (const float*)d_in[29];
    const float* reg_b1 = (const float*)d_in[30];
    const float* p_w1   = (const float*)d_in[31];
    const float* p_b1   = (const float*)d_in[32];
    const float* p_w2   = (const float*)d_in[33];
    const float* p_b2   = (const float*)d_in[34];
    const float* b_scale = (const float*)d_in[35];
    const float* b_bias  = (const float*)d_in[36];
    float* out = (float*)d_out;

    char* wsb = (char*)d_ws;
    __hip_bfloat16* feature = (__hip_bfloat16*)(wsb + 0);          // [6144][512]
    __hip_bfloat16* qkvb    = (__hip_bfloat16*)(wsb + 6291456);    // [6144][1536]
    __hip_bfloat16* tb      = (__hip_bfloat16*)(wsb + 25165824);   // [6144][512]
    __hip_bfloat16* vtb     = (__hip_bfloat16*)(wsb + 31457280);   // Vt [32][128][768]
    __hip_bfloat16* rb      = (__hip_bfloat16*)(wsb + 31457280);   // wo out (after fattn)
    __hip_bfloat16* hb      = (__hip_bfloat16*)(wsb + 37748736);   // [6144][1024]
    __hip_bfloat16* f2      = (__hip_bfloat16*)(wsb + 50331648);   // [6144][512]
    __hip_bfloat16* clsregb = (__hip_bfloat16*)(wsb + 56623104);   // [6144][1024]
    __hip_bfloat16* phb     = (__hip_bfloat16*)(wsb + 69206016);   // [6144][1024]
    float* of1 = (float*)(wsb + 6291456);
    float* of2 = (float*)(wsb + 8595456);
    __hip_bfloat16* fe1 = (__hip_bfloat16*)(wsb + 9171456);
    __hip_bfloat16* fe2 = (__hip_bfloat16*)(wsb + 11475456);
    __hip_bfloat16* fsb = (__hip_bfloat16*)(wsb + 25165824);       // smp [6144][2688]
    __hip_bfloat16* fe0 = (__hip_bfloat16*)(wsb + 58195968);
    float* of0 = (float*)(wsb + 67411968);
    __hip_bfloat16* wqkv_bf   = (__hip_bfloat16*)(wsb + 81788928); // [1536][512]
    __hip_bfloat16* wo_bf     = (__hip_bfloat16*)(wsb + 83361792);
    __hip_bfloat16* cf1_bf    = (__hip_bfloat16*)(wsb + 83886080);
    __hip_bfloat16* cf2_bf    = (__hip_bfloat16*)(wsb + 84934656);
    __hip_bfloat16* clsreg_bf = (__hip_bfloat16*)(wsb + 85983232); // [1024][512]
    __hip_bfloat16* p1_bf     = (__hip_bfloat16*)(wsb + 87031808);
    __hip_bfloat16* gfw2_bf   = (__hip_bfloat16*)(wsb + 88080384); // [512][672]
    float* bqkv    = (float*)(wsb + 88768512);
    float* bclsreg = (float*)(wsb + 88774656);
    float* b2      = (float*)(wsb + 88778752);

    k_wprep<<<3587, 256, 0, stream>>>(
        wq, wk, wv, wo, cf_w1, cf_w2, cls_w1, reg_w1, p_w1, bq, bk, bv, cls_b1, reg_b1,
        gf_w, dp_w, dp_b, gf_b,
        wqkv_bf, wo_bf, cf1_bf, cf2_bf, clsreg_bf, p1_bf, gfw2_bf, b2, bqkv, bclsreg);

    k_adjoff<<<dim3(63, BB), 256, 0, stream>>>(feat0, ca_w, ca_b, off_w, off_b,
                                               fe0, of0, H0 * W0, 1);
    k_adjr12<<<160 + (BB * (H1 * W1 + H2 * W2) * CADJ + 255) / 256, 256, 0, stream>>>(
        feat1, feat2, ca_w, ca_b, fe1, fe2, of0, of1, of2);
    k_sample<<<3072, 256, 0, stream>>>(priors, fe0, fe1, fe2, of0, of1, of2, z_emb, fsb);

    const int M = BB * PP;
    k_bgemm64<<<dim3(2, M / 64, 4), 256, 0, stream>>>(
        fsb, 2688, 672, gfw2_bf, 672, 128 * 672, b2, 128,
        nullptr, 0, feature, DD, 128, 672, 0);
    k_bgemm<<<dim3(12, M / 128, 1), 256, 0, stream>>>(
        feature, DD, 0, wqkv_bf, DD, 0, bqkv, 0,
        nullptr, 0, qkvb, 1536, 0, DD, 0);
    k_vt<<<dim3(12, 32), 256, 0, stream>>>(qkvb, vtb);
    k_fattn<<<384, 256, 0, stream>>>(qkvb, vtb, tb);
    k_bgemm64<<<dim3(8, M / 64, 1), 256, 0, stream>>>(
        tb, DD, 0, wo_bf, DD, 0, bo, 0, nullptr, 0, rb, DD, 0, DD, 0);
    k_bgemm64<<<dim3(16, M / 64, 1), 256, 0, stream>>>(
        rb, DD, 0, cf1_bf, DD, 0, cf_b1, 0, nullptr, 0, hb, 1024, 0, DD, 1);
    k_bgemm64<<<dim3(8, M / 64, 1), 256, 0, stream>>>(
        hb, 1024, 0, cf2_bf, 1024, 0, cf_b2, 0, feature, DD, f2, DD, 0, 1024, 0);
    k_bgemm64<<<dim3(16, M / 64, 1), 256, 0, stream>>>(
        f2, DD, 0, clsreg_bf, DD, 0, bclsreg, 0, nullptr, 0, clsregb, 1024, 0, DD, 1);
    k_bgemm64<<<dim3(16, M / 64, 1), 256, 0, stream>>>(
        clsregb + 512, 1024, 0, p1_bf, DD, 0, p_b1, 0, nullptr, 0, phb, 1024, 0, DD, 1);

    k_head<<<M / 4, 256, 0, stream>>>(clsregb, phb, cls_w2, cls_b2, p_w2, p_b2, b_scale, b_bias, out);
}